// Round 10
// baseline (90.703 us; speedup 1.0000x reference)
//
#include <hip/hip_runtime.h>

typedef __attribute__((ext_vector_type(8))) short short8;
typedef __attribute__((ext_vector_type(4))) float f32x4;
typedef unsigned int u32;

#define ROW_B 1056          // 66 w-chunks * 16 B (8 bf16 channels per chunk); 64 written, 2 pad
#define SLOT_B 10560        // 10 h-rows per d-plane
#define NSLOT 4
#define CSTRIDE 131072      // channel stride in x (elements): 32*64*64

__device__ __forceinline__ unsigned short f2bf(float f) {
  unsigned u = __builtin_bit_cast(unsigned, f);
  u += 0x7FFFu + ((u >> 16) & 1u);          // RNE (inputs finite)
  return (unsigned short)(u >> 16);
}
__device__ __forceinline__ u32 cvtpk(float lo, float hi) {
  u32 r;
  asm("v_cvt_pk_bf16_f32 %0, %1, %2" : "=v"(r) : "v"(lo), "v"(hi));
  return r;
}

// Inter-plane sync: ds-ops complete (lgkmcnt 0); in-flight global loads stay
// outstanding across the barrier (NO vmcnt drain).
#define LBAR()                                                                \
  {                                                                           \
    asm volatile("s_waitcnt lgkmcnt(0)" ::: "memory");                        \
    __builtin_amdgcn_s_barrier();                                             \
    __builtin_amdgcn_sched_barrier(0);                                        \
  }

#define MFMA1(A, B, C) __builtin_amdgcn_mfma_f32_16x16x32_bf16(A, B, C, 0, 0, 0)

// LDS fragment read: slot base SB, w-tile WT, row R
#define RDF(SB, WT, R) (*(const short8*)(smem + (SB) + (R) * ROW_B + physoff[WT]))

// 18-MFMA group for one w-tile column WT from fragments F0..F3 (rows r..r+3).
// K0: open gen dp (C=0 trick); K1: gen dp-1 (kd=1); K2: gen dp-2 (kd=2).
#define MGRP(F0, F1, F2, F3, WT, AN, AM, AO, K0, K1, K2)                      \
  {                                                                           \
    if (K0) {                                                                 \
      AN[0][WT] = MFMA1(F0, bfragB[0][0], zf4);                               \
      AN[1][WT] = MFMA1(F1, bfragB[0][0], zf4);                               \
      AN[0][WT] = MFMA1(F1, bfragB[0][1], AN[0][WT]);                         \
      AN[1][WT] = MFMA1(F2, bfragB[0][1], AN[1][WT]);                         \
      AN[0][WT] = MFMA1(F2, bfragB[0][2], AN[0][WT]);                         \
      AN[1][WT] = MFMA1(F3, bfragB[0][2], AN[1][WT]);                         \
    }                                                                         \
    if (K1) {                                                                 \
      AM[0][WT] = MFMA1(F0, bfragB[1][0], AM[0][WT]);                         \
      AM[1][WT] = MFMA1(F1, bfragB[1][0], AM[1][WT]);                         \
      AM[0][WT] = MFMA1(F1, bfragB[1][1], AM[0][WT]);                         \
      AM[1][WT] = MFMA1(F2, bfragB[1][1], AM[1][WT]);                         \
      AM[0][WT] = MFMA1(F2, bfragB[1][2], AM[0][WT]);                         \
      AM[1][WT] = MFMA1(F3, bfragB[1][2], AM[1][WT]);                         \
    }                                                                         \
    if (K2) {                                                                 \
      AO[0][WT] = MFMA1(F0, bfragB[2][0], AO[0][WT]);                         \
      AO[1][WT] = MFMA1(F1, bfragB[2][0], AO[1][WT]);                         \
      AO[0][WT] = MFMA1(F1, bfragB[2][1], AO[0][WT]);                         \
      AO[1][WT] = MFMA1(F2, bfragB[2][1], AO[1][WT]);                         \
      AO[0][WT] = MFMA1(F2, bfragB[2][2], AO[0][WT]);                         \
      AO[1][WT] = MFMA1(F3, bfragB[2][2], AO[1][WT]);                         \
    }                                                                         \
  }

// PROC(dp): MFMA wt0 from PFC (prefetched LAST plane -> no post-barrier LDS
// wait); roll in-plane reads one group ahead (wt1..wt3 hide under preceding
// MFMA groups); prefetch plane dp+1 wt0 into PFN (slot written in PROC(dp-2),
// 2 barriers ago - race-free with lookahead-3 staging); tail: cvt+ds_write
// plane dp+3, issue loads plane dp+4, pool-close gen dp-2; lgkm-only barrier.
#define PROC(DP, AN, AM, AO, PFC, PFN, K0, K1, K2, CL, SV, WR, LD, PF, BAR)   \
  {                                                                           \
    const int dp_  = (DP);                                                    \
    const int sb_  = (dp_ & 3) * SLOT_B + rowbase;                            \
    const int sbn_ = ((dp_ + 1) & 3) * SLOT_B + rowbase;                      \
    short8 t1_0 = RDF(sb_, 1, 0), t1_1 = RDF(sb_, 1, 1),                      \
           t1_2 = RDF(sb_, 1, 2), t1_3 = RDF(sb_, 1, 3);                      \
    __builtin_amdgcn_s_setprio(1);                                            \
    MGRP(PFC[0], PFC[1], PFC[2], PFC[3], 0, AN, AM, AO, K0, K1, K2);          \
    short8 t2_0 = RDF(sb_, 2, 0), t2_1 = RDF(sb_, 2, 1),                      \
           t2_2 = RDF(sb_, 2, 2), t2_3 = RDF(sb_, 2, 3);                      \
    MGRP(t1_0, t1_1, t1_2, t1_3, 1, AN, AM, AO, K0, K1, K2);                  \
    short8 t3_0 = RDF(sb_, 3, 0), t3_1 = RDF(sb_, 3, 1),                      \
           t3_2 = RDF(sb_, 3, 2), t3_3 = RDF(sb_, 3, 3);                      \
    MGRP(t2_0, t2_1, t2_2, t2_3, 2, AN, AM, AO, K0, K1, K2);                  \
    if (PF) {                                                                 \
      PFN[0] = RDF(sbn_, 0, 0); PFN[1] = RDF(sbn_, 0, 1);                     \
      PFN[2] = RDF(sbn_, 0, 2); PFN[3] = RDF(sbn_, 0, 3);                     \
    }                                                                         \
    MGRP(t3_0, t3_1, t3_2, t3_3, 3, AN, AM, AO, K0, K1, K2);                  \
    __builtin_amdgcn_s_setprio(0);                                            \
    if (WR) stage_write(dp_ + 3);                                             \
    if (LD) stage_load(dp_ + 4);                                              \
    if (CL) {                                                                 \
      _Pragma("unroll") for (int wt = 0; wt < 4; ++wt) {                      \
        const float e01 = fmaxf(fmaxf(AO[0][wt][0], AO[0][wt][1]),            \
                                fmaxf(AO[1][wt][0], AO[1][wt][1]));           \
        const float e23 = fmaxf(fmaxf(AO[0][wt][2], AO[0][wt][3]),            \
                                fmaxf(AO[1][wt][2], AO[1][wt][3]));           \
        if (SV) {                                                             \
          p01[wt] = e01; p23[wt] = e23;                                       \
        } else if (hvalid) {                                                  \
          sum += fmaxf(p01[wt], e01);                                         \
          if (!(wt == 3 && g == 3)) sum += fmaxf(p23[wt], e23);               \
        }                                                                     \
      }                                                                       \
    }                                                                         \
    if (BAR) LBAR()                                                           \
  }

// grid: 512 = 64 b * 8 h-octets ; block: 256 (4 waves x 2 h'-rows each)
__launch_bounds__(256, 2)
__global__ void conv_fused(const float* __restrict__ x,
                           const float* __restrict__ cw,
                           float* __restrict__ ws) {
  __shared__ __align__(16) unsigned char smem[NSLOT * SLOT_B];
  __shared__ float wsum[4];

  // XCD-chunked bijective swizzle (512 % 8 == 0)
  const int rb  = blockIdx.x;
  const int bid = (rb & 7) * 64 + (rb >> 3);
  const int b   = bid >> 3;
  const int hq  = bid & 7;
  const int h0  = hq * 8;

  const int tid  = threadIdx.x;
  const int lane = tid & 63;
  const int wid  = tid >> 6;
  const int nm   = lane & 15;
  const int g    = lane >> 4;

  const float* xb = x + (size_t)b * (8u * 32u * 64u * 64u);

  // ---- B fragments: 9 (kd,kh) weight-sets, K = kw*8 + c (24 used, 8 pad) ----
  short8 bfragB[3][3];
#pragma unroll
  for (int kd = 0; kd < 3; ++kd)
#pragma unroll
    for (int kh = 0; kh < 3; ++kh) {
      short8 f;
#pragma unroll
      for (int j = 0; j < 8; ++j) {
        float v = (g < 3) ? cw[(nm * 8 + j) * 27 + kd * 9 + kh * 3 + g] : 0.f;
        f[j] = (short)f2bf(v);
      }
      bfragB[kd][kh] = f;
    }

  // ---- A-fragment chunk offsets (reads bank-conflict-free by pigeonhole) ----
  const int gc = (g < 3) ? g : 2;     // pad lanes read real data, weight = 0
  int physoff[4];
#pragma unroll
  for (int wt = 0; wt < 4; ++wt) physoff[wt] = (wt * 16 + nm + gc) * 16;
  const int rowbase = (2 * wid) * ROW_B;

  // ---- staging: slot s = row*64 + w ; thread gathers 8 channels, one b128
  // write. Block-uniform channel bases (SGPR) + loop-invariant VGPR offset.
  bool st_act[3]; int st_toff[3]; int st_off[3];
#pragma unroll
  for (int pass = 0; pass < 3; ++pass) {
    const int t = tid + pass * 256;
    bool act = (t < 640);
    int row = (t >> 6) % 10;
    const int w = t & 63;
    int h = h0 + row;
    if (h > 63) { act = false; h = 63; }
    st_act[pass]  = act;
    st_toff[pass] = h * 64 + w;
    st_off[pass]  = row * ROW_B + w * 16;
  }

  float ld[3][8];   // single in-flight staging buffer (24 VGPRs)

  auto stage_load = [&](int p) {
    const int pbase = p * 4096;
#pragma unroll
    for (int pass = 0; pass < 3; ++pass) {
      if (st_act[pass]) {
        const int o = st_toff[pass] + pbase;
#pragma unroll
        for (int c = 0; c < 8; ++c)
          ld[pass][c] = (xb + (size_t)c * CSTRIDE)[o];
      }
    }
  };
  auto stage_write = [&](int p) {
    unsigned char* d = smem + (p & 3) * SLOT_B;
#pragma unroll
    for (int pass = 0; pass < 3; ++pass) {
      if (st_act[pass]) {
        uint4 v;
        v.x = cvtpk(ld[pass][0], ld[pass][1]);
        v.y = cvtpk(ld[pass][2], ld[pass][3]);
        v.z = cvtpk(ld[pass][4], ld[pass][5]);
        v.w = cvtpk(ld[pass][6], ld[pass][7]);
        *(uint4*)(d + st_off[pass]) = v;
      }
    }
  };

  const bool hvalid = !(hq == 7 && wid == 3);  // h' 62,63 invalid
  const f32x4 zf4 = {0.f, 0.f, 0.f, 0.f};
  float sum = 0.f;
  float p01[4], p23[4];
  f32x4 accA[2][4], accB[2][4], accC[2][4];    // gen % 3 rotation
  short8 pfA[4], pfB[4];                       // cross-barrier wt0 prefetch

  // prologue: planes 0,1,2 staged synchronously; plane-3 loads in flight
  stage_load(0); stage_write(0);
  stage_load(1); stage_write(1);
  stage_load(2); stage_write(2);
  stage_load(3);
  LBAR()
  // prefetch plane 0 wt0 (post-barrier: all writes of plane 0 visible)
  {
    const int pb_ = 0 * SLOT_B + rowbase;
    pfA[0] = RDF(pb_, 0, 0); pfA[1] = RDF(pb_, 0, 1);
    pfA[2] = RDF(pb_, 0, 2); pfA[3] = RDF(pb_, 0, 3);
  }

  //            AN    AM    AO    PFC  PFN  K0 K1 K2 CL SV WR LD PF BAR
  PROC(0, accA, accB, accC, pfA, pfB, 1, 0, 0, 0, 0, 1, 1, 1, 1)  // wr3 ld4
  PROC(1, accB, accA, accC, pfB, pfA, 1, 1, 0, 0, 0, 1, 1, 1, 1)  // wr4 ld5

  // main: dp = 2..25, closures d' = 0..23 (even=save, odd=combine)
  for (int p0 = 2; p0 <= 20; p0 += 6) {
    PROC(p0 + 0, accC, accB, accA, pfA, pfB, 1, 1, 1, 1, 1, 1, 1, 1, 1)
    PROC(p0 + 1, accA, accC, accB, pfB, pfA, 1, 1, 1, 1, 0, 1, 1, 1, 1)
    PROC(p0 + 2, accB, accA, accC, pfA, pfB, 1, 1, 1, 1, 1, 1, 1, 1, 1)
    PROC(p0 + 3, accC, accB, accA, pfB, pfA, 1, 1, 1, 1, 0, 1, 1, 1, 1)
    PROC(p0 + 4, accA, accC, accB, pfA, pfB, 1, 1, 1, 1, 1, 1, 1, 1, 1)
    PROC(p0 + 5, accB, accA, accC, pfB, pfA, 1, 1, 1, 1, 0, 1, 1, 1, 1)
  }
  // epilogue: dp = 26..31 (writes end at plane 31 in PROC(28); loads at 31 in
  // PROC(27); gens 30,31 never opened)
  PROC(26, accC, accB, accA, pfA, pfB, 1, 1, 1, 1, 1, 1, 1, 1, 1)
  PROC(27, accA, accC, accB, pfB, pfA, 1, 1, 1, 1, 0, 1, 1, 1, 1)
  PROC(28, accB, accA, accC, pfA, pfB, 1, 1, 1, 1, 1, 1, 0, 1, 1)
  PROC(29, accC, accB, accA, pfB, pfA, 1, 1, 1, 1, 0, 0, 0, 1, 1)
  PROC(30, accA, accC, accB, pfA, pfB, 0, 1, 1, 1, 1, 0, 0, 1, 1)
  PROC(31, accB, accA, accC, pfB, pfA, 0, 0, 1, 1, 0, 0, 0, 0, 0)

  // block reduce -> one partial per block (stored by LOGICAL bid)
#pragma unroll
  for (int off = 32; off > 0; off >>= 1) sum += __shfl_down(sum, off);
  if (lane == 0) wsum[wid] = sum;
  __syncthreads();
  if (tid == 0) ws[bid] = wsum[0] + wsum[1] + wsum[2] + wsum[3];
}

// out[b] = 0.5 * S_b / 14415 + 0.5 * sum(conv_bias) + sum(bias)
__global__ void finalize_k(const float* __restrict__ ws,
                           const float* __restrict__ cb,
                           const float* __restrict__ bias,
                           float* __restrict__ out) {
  const int b = threadIdx.x;
  float s = 0.f;
#pragma unroll
  for (int hq = 0; hq < 8; ++hq) s += ws[b * 8 + hq];
  float cbs = 0.f, bs = 0.f;
#pragma unroll
  for (int c = 0; c < 16; ++c) { cbs += cb[c]; bs += bias[c]; }
  out[b] = 0.5f * s / 14415.f + 0.5f * cbs + bs;
}

extern "C" void kernel_launch(void* const* d_in, const int* in_sizes, int n_in,
                              void* d_out, int out_size, void* d_ws, size_t ws_size,
                              hipStream_t stream) {
  const float* x    = (const float*)d_in[0];
  const float* cw   = (const float*)d_in[1];
  const float* cb   = (const float*)d_in[2];
  const float* bias = (const float*)d_in[3];
  float* out = (float*)d_out;
  float* ws  = (float*)d_ws;   // 512 floats

  hipLaunchKernelGGL(conv_fused, dim3(512), dim3(256), 0, stream, x, cw, ws);
  hipLaunchKernelGGL(finalize_k, dim3(1), dim3(64), 0, stream, ws, cb, bias, out);
}

// Round 11
// 78.799 us; speedup vs baseline: 1.1511x; 1.1511x over previous
//
#include <hip/hip_runtime.h>

typedef __attribute__((ext_vector_type(8))) short short8;
typedef __attribute__((ext_vector_type(4))) float f32x4;
typedef unsigned int u32;

#define SLOT_B 4096         // 4 rows * 64 w * 16 B (8 bf16 channels)
#define NSLOT 4
#define CSTRIDE 131072      // channel stride in x (elements): 32*64*64

__device__ __forceinline__ unsigned short f2bf(float f) {
  unsigned u = __builtin_bit_cast(unsigned, f);
  u += 0x7FFFu + ((u >> 16) & 1u);          // RNE (inputs finite)
  return (unsigned short)(u >> 16);
}
__device__ __forceinline__ u32 cvtpk(float lo, float hi) {
  u32 r;
  asm("v_cvt_pk_bf16_f32 %0, %1, %2" : "=v"(r) : "v"(lo), "v"(hi));
  return r;
}

#define MFMA1(A, B, C) __builtin_amdgcn_mfma_f32_16x16x32_bf16(A, B, C, 0, 0, 0)

// 18-MFMA group for w-tile WT from row-fragments F0..F3 (rows 0..3 of plane).
// K0: open gen dp (C=0); K1: gen dp-1 (kd=1); K2: gen dp-2 (kd=2).
#define MGRP(F0, F1, F2, F3, WT, AN, AM, AO, K0, K1, K2)                      \
  {                                                                           \
    if (K0) {                                                                 \
      AN[0][WT] = MFMA1(F0, bfragB[0][0], zf4);                               \
      AN[1][WT] = MFMA1(F1, bfragB[0][0], zf4);                               \
      AN[0][WT] = MFMA1(F1, bfragB[0][1], AN[0][WT]);                         \
      AN[1][WT] = MFMA1(F2, bfragB[0][1], AN[1][WT]);                         \
      AN[0][WT] = MFMA1(F2, bfragB[0][2], AN[0][WT]);                         \
      AN[1][WT] = MFMA1(F3, bfragB[0][2], AN[1][WT]);                         \
    }                                                                         \
    if (K1) {                                                                 \
      AM[0][WT] = MFMA1(F0, bfragB[1][0], AM[0][WT]);                         \
      AM[1][WT] = MFMA1(F1, bfragB[1][0], AM[1][WT]);                         \
      AM[0][WT] = MFMA1(F1, bfragB[1][1], AM[0][WT]);                         \
      AM[1][WT] = MFMA1(F2, bfragB[1][1], AM[1][WT]);                         \
      AM[0][WT] = MFMA1(F2, bfragB[1][2], AM[0][WT]);                         \
      AM[1][WT] = MFMA1(F3, bfragB[1][2], AM[1][WT]);                         \
    }                                                                         \
    if (K2) {                                                                 \
      AO[0][WT] = MFMA1(F0, bfragB[2][0], AO[0][WT]);                         \
      AO[1][WT] = MFMA1(F1, bfragB[2][0], AO[1][WT]);                         \
      AO[0][WT] = MFMA1(F1, bfragB[2][1], AO[0][WT]);                         \
      AO[1][WT] = MFMA1(F2, bfragB[2][1], AO[1][WT]);                         \
      AO[0][WT] = MFMA1(F2, bfragB[2][2], AO[0][WT]);                         \
      AO[1][WT] = MFMA1(F3, bfragB[2][2], AO[1][WT]);                         \
    }                                                                         \
  }

// Barrier-free PROC(dp): issue loads(dp+2) -> 72-MFMA burst on plane dp
// (slot dp&3) -> cvt+ds_write(dp+2) (loads ~1400cyc old: latency hidden)
// -> pool-close gen dp-2. NO barrier: wave-private LDS; slot (dp+2)&3 was
// read 2 PROCs ago in this wave's own program order (DS in-order; the two
// sched_barrier(0)s block compiler hoisting). Waves free-run and de-phase.
#define PROC(DP, AN, AM, AO, K0, K1, K2, CL, SV, ST)                          \
  {                                                                           \
    const int dp_ = (DP);                                                     \
    if (ST) {                                                                 \
      stage_load(dp_ + 2);                                                    \
      __builtin_amdgcn_sched_barrier(0);                                      \
    }                                                                         \
    const int sb_ = (dp_ & 3) * SLOT_B;                                       \
    __builtin_amdgcn_s_setprio(1);                                            \
    _Pragma("unroll") for (int wt = 0; wt < 4; ++wt) {                        \
      const short8 f0 = *(const short8*)(smem + sb_ + 0 * 1024 + physoff[wt]); \
      const short8 f1 = *(const short8*)(smem + sb_ + 1 * 1024 + physoff[wt]); \
      const short8 f2 = *(const short8*)(smem + sb_ + 2 * 1024 + physoff[wt]); \
      const short8 f3 = *(const short8*)(smem + sb_ + 3 * 1024 + physoff[wt]); \
      MGRP(f0, f1, f2, f3, wt, AN, AM, AO, K0, K1, K2);                       \
    }                                                                         \
    __builtin_amdgcn_s_setprio(0);                                            \
    __builtin_amdgcn_sched_barrier(0);                                        \
    if (ST) stage_write(dp_ + 2);                                             \
    if (CL) {                                                                 \
      _Pragma("unroll") for (int wt = 0; wt < 4; ++wt) {                      \
        const float e01 = fmaxf(fmaxf(AO[0][wt][0], AO[0][wt][1]),            \
                                fmaxf(AO[1][wt][0], AO[1][wt][1]));           \
        const float e23 = fmaxf(fmaxf(AO[0][wt][2], AO[0][wt][3]),            \
                                fmaxf(AO[1][wt][2], AO[1][wt][3]));           \
        if (SV) {                                                             \
          p01[wt] = e01; p23[wt] = e23;                                       \
        } else {                                                              \
          sum += fmaxf(p01[wt], e01);                                         \
          if (!(wt == 3 && g == 3)) sum += fmaxf(p23[wt], e23);               \
        }                                                                     \
      }                                                                       \
    }                                                                         \
  }

// grid: 1984 = 64 b * 31 h'-pairs ; block: 64 (ONE wave, fully independent)
__launch_bounds__(64, 2)
__global__ void conv_fused(const float* __restrict__ x,
                           const float* __restrict__ cw,
                           float* __restrict__ ws) {
  // wave-private LDS ring; +32 B pad absorbs the w-chunk-65 overread of
  // invalid outputs w'=62,63 (finite garbage, discarded by wmask)
  __shared__ __align__(16) unsigned char smem[NSLOT * SLOT_B + 32];

  // XCD-chunked bijective swizzle (1984 = 8*248): 248 consecutive logical
  // blocks (8 images' 31 h-pairs) per XCD -> halo rows shared in same L2.
  const int rb  = blockIdx.x;
  const int bid = (rb & 7) * 248 + (rb >> 3);
  const int b   = bid / 31;
  const int q   = bid - 31 * b;      // h'-pair index: outputs h' = 2q, 2q+1
  const int h0  = 2 * q;             // input rows h0..h0+3

  const int lane = threadIdx.x;      // 0..63
  const int nm   = lane & 15;
  const int g    = lane >> 4;

  const float* xb = x + (size_t)b * (8u * 32u * 64u * 64u);

  // ---- B fragments: 9 (kd,kh) weight-sets, K = kw*8 + c (24 used, 8 pad) ----
  short8 bfragB[3][3];
#pragma unroll
  for (int kd = 0; kd < 3; ++kd)
#pragma unroll
    for (int kh = 0; kh < 3; ++kh) {
      short8 f;
#pragma unroll
      for (int j = 0; j < 8; ++j) {
        float v = (g < 3) ? cw[(nm * 8 + j) * 27 + kd * 9 + kh * 3 + g] : 0.f;
        f[j] = (short)f2bf(v);
      }
      bfragB[kd][kh] = f;
    }

  // ---- A-fragment chunk offsets (reads bank-conflict-free by pigeonhole) ----
  const int gc = (g < 3) ? g : 2;     // pad lanes read real data, weight = 0
  int physoff[4];
#pragma unroll
  for (int wt = 0; wt < 4; ++wt) physoff[wt] = (wt * 16 + nm + gc) * 16;

  // ---- wave-private staging: 4 rows x 64 w; lane owns w=lane of all 4 rows.
  // Loads: SGPR channel base + invariant VGPR offset; 8 ch gathered -> one
  // ds_write_b128 per row (lane-consecutive: conflict-free).
  int o_base[4];
#pragma unroll
  for (int s = 0; s < 4; ++s) o_base[s] = (h0 + s) * 64 + lane;

  float ld[4][8];   // 32 VGPRs, single in-flight generation

  auto stage_load = [&](int p) {
    const int pbase = p * 4096;
#pragma unroll
    for (int s = 0; s < 4; ++s) {
      const int o = o_base[s] + pbase;
#pragma unroll
      for (int c = 0; c < 8; ++c)
        ld[s][c] = (xb + (size_t)c * CSTRIDE)[o];
    }
  };
  auto stage_write = [&](int p) {
    unsigned char* d = smem + (p & 3) * SLOT_B + lane * 16;
#pragma unroll
    for (int s = 0; s < 4; ++s) {
      uint4 v;
      v.x = cvtpk(ld[s][0], ld[s][1]);
      v.y = cvtpk(ld[s][2], ld[s][3]);
      v.z = cvtpk(ld[s][4], ld[s][5]);
      v.w = cvtpk(ld[s][6], ld[s][7]);
      *(uint4*)(d + s * 1024) = v;
    }
  };

  const f32x4 zf4 = {0.f, 0.f, 0.f, 0.f};
  float sum = 0.f;
  float p01[4], p23[4];
  f32x4 accA[2][4], accB[2][4], accC[2][4];    // gen % 3 rotation

  // prologue: planes 0,1 staged; no barrier needed (private data)
  stage_load(0); stage_write(0);
  stage_load(1); stage_write(1);

  //            AN    AM    AO    K0 K1 K2 CL SV ST
  PROC(0, accA, accB, accC, 1, 0, 0, 0, 0, 1)   // stage 2
  PROC(1, accB, accA, accC, 1, 1, 0, 0, 0, 1)   // stage 3

  // main: dp = 2..25, closures d' = 0..23 (even=save, odd=combine)
  for (int p0 = 2; p0 <= 20; p0 += 6) {
    PROC(p0 + 0, accC, accB, accA, 1, 1, 1, 1, 1, 1)
    PROC(p0 + 1, accA, accC, accB, 1, 1, 1, 1, 0, 1)
    PROC(p0 + 2, accB, accA, accC, 1, 1, 1, 1, 1, 1)
    PROC(p0 + 3, accC, accB, accA, 1, 1, 1, 1, 0, 1)
    PROC(p0 + 4, accA, accC, accB, 1, 1, 1, 1, 1, 1)
    PROC(p0 + 5, accB, accA, accC, 1, 1, 1, 1, 0, 1)
  }
  // epilogue: dp = 26..31 (last stage: plane 31 at PROC(29); gens 30,31 skipped)
  PROC(26, accC, accB, accA, 1, 1, 1, 1, 1, 1)
  PROC(27, accA, accC, accB, 1, 1, 1, 1, 0, 1)
  PROC(28, accB, accA, accC, 1, 1, 1, 1, 1, 1)
  PROC(29, accC, accB, accA, 1, 1, 1, 1, 0, 1)
  PROC(30, accA, accC, accB, 0, 1, 1, 1, 1, 0)
  PROC(31, accB, accA, accC, 0, 0, 1, 1, 0, 0)

  // wave reduce -> one partial per wave-tile (stored by LOGICAL bid)
#pragma unroll
  for (int off = 32; off > 0; off >>= 1) sum += __shfl_down(sum, off);
  if (lane == 0) ws[bid] = sum;
}

// out[b] = 0.5 * S_b / 14415 + 0.5 * sum(conv_bias) + sum(bias)
__global__ void finalize_k(const float* __restrict__ ws,
                           const float* __restrict__ cb,
                           const float* __restrict__ bias,
                           float* __restrict__ out) {
  const int b = threadIdx.x;
  float s = 0.f;
#pragma unroll
  for (int q = 0; q < 31; ++q) s += ws[b * 31 + q];
  float cbs = 0.f, bs = 0.f;
#pragma unroll
  for (int c = 0; c < 16; ++c) { cbs += cb[c]; bs += bias[c]; }
  out[b] = 0.5f * s / 14415.f + 0.5f * cbs + bs;
}

extern "C" void kernel_launch(void* const* d_in, const int* in_sizes, int n_in,
                              void* d_out, int out_size, void* d_ws, size_t ws_size,
                              hipStream_t stream) {
  const float* x    = (const float*)d_in[0];
  const float* cw   = (const float*)d_in[1];
  const float* cb   = (const float*)d_in[2];
  const float* bias = (const float*)d_in[3];
  float* out = (float*)d_out;
  float* ws  = (float*)d_ws;   // 1984 floats

  hipLaunchKernelGGL(conv_fused, dim3(1984), dim3(64), 0, stream, x, cw, ws);
  hipLaunchKernelGGL(finalize_k, dim3(1), dim3(64), 0, stream, ws, cb, bias, out);
}